// Round 2
// baseline (693.001 us; speedup 1.0000x reference)
//
#include <hip/hip_runtime.h>

#define R_ 8
#define N_ 40000
#define F_ 128
#define E_ 160000

// --- K1: alpha[r] = sigmoid(tanh(rel @ w1 + b1) @ w2); also copy rel_mat to out tail ---
__global__ void alpha_and_rel_kernel(const float* __restrict__ rel,
                                     const float* __restrict__ w1,
                                     const float* __restrict__ b1,
                                     const float* __restrict__ w2,
                                     float* __restrict__ alpha,
                                     float* __restrict__ out_tail) {
    int r = blockIdx.x;          // 0..7
    int o = threadIdx.x;         // 0..127
    __shared__ float relrow[F_];
    __shared__ float red[F_];
    float rv = rel[r * F_ + o];
    relrow[o] = rv;
    out_tail[r * F_ + o] = rv;   // output[1] = rel_mat passthrough
    __syncthreads();
    float s = 0.f;
#pragma unroll 8
    for (int f = 0; f < F_; ++f)
        s += relrow[f] * w1[f * F_ + o];   // coalesced across o
    float h = tanhf(s + b1[o]);
    red[o] = h * w2[o];
    __syncthreads();
    for (int off = 64; off > 0; off >>= 1) {
        if (o < off) red[o] += red[o + off];
        __syncthreads();
    }
    if (o == 0) alpha[r] = 1.f / (1.f + expf(-red[0]));
}

// --- K2: proj = ent_mat @ weight_ent (N x F fp32) ---
__global__ void proj_kernel(const float* __restrict__ ent,
                            const float* __restrict__ W,
                            float* __restrict__ proj) {
    int n = blockIdx.x;          // 0..N-1
    int o = threadIdx.x;         // 0..127
    __shared__ float row[F_];
    row[o] = ent[n * F_ + o];
    __syncthreads();
    float s = 0.f;
#pragma unroll 8
    for (int f = 0; f < F_; ++f)
        s += row[f] * W[f * F_ + o];       // coalesced across o, W is L1-resident
    proj[n * F_ + o] = s;
}

// --- K3: fused scatter: out[src] += alpha[r]*val * proj[dst], one wave per edge ---
__global__ void scatter_kernel(const int* __restrict__ esrc,
                               const int* __restrict__ edst,
                               const float* __restrict__ eval_,
                               const float* __restrict__ alpha,
                               const float* __restrict__ proj,
                               float* __restrict__ acc) {
    int gtid = blockIdx.x * blockDim.x + threadIdx.x;
    int wave = gtid >> 6;
    int lane = threadIdx.x & 63;
    int nw = (gridDim.x * blockDim.x) >> 6;
    for (int e = wave; e < R_ * E_; e += nw) {
        int r = e / E_;                    // const-div -> magic mul
        float w = alpha[r] * eval_[e];
        int s = esrc[e];
        int d = edst[e];
        float p0 = proj[d * F_ + lane];         // 256B coalesced
        float p1 = proj[d * F_ + 64 + lane];    // 256B coalesced
        atomicAdd(&acc[s * F_ + lane], w * p0);
        atomicAdd(&acc[s * F_ + 64 + lane], w * p1);
    }
}

extern "C" void kernel_launch(void* const* d_in, const int* in_sizes, int n_in,
                              void* d_out, int out_size, void* d_ws, size_t ws_size,
                              hipStream_t stream) {
    const float* ent   = (const float*)d_in[0];
    const float* rel   = (const float*)d_in[1];
    const int*   esrc  = (const int*)d_in[2];
    const int*   edst  = (const int*)d_in[3];
    const float* eval_ = (const float*)d_in[4];
    const float* went  = (const float*)d_in[5];
    const float* w1    = (const float*)d_in[6];
    const float* b1    = (const float*)d_in[7];
    const float* w2    = (const float*)d_in[8];

    float* out      = (float*)d_out;
    float* out_tail = out + (size_t)N_ * F_;       // rel_mat passthrough (R*F)

    char*  ws    = (char*)d_ws;
    float* proj  = (float*)ws;                                  // N*F fp32 = 20.48 MB
    float* alpha = (float*)(ws + (size_t)N_ * F_ * 4);          // 8 floats

    // out[0] region doubles as the fp32 accumulator; harness poisons it, so zero it.
    hipMemsetAsync(out, 0, (size_t)N_ * F_ * sizeof(float), stream);
    alpha_and_rel_kernel<<<R_, F_, 0, stream>>>(rel, w1, b1, w2, alpha, out_tail);
    proj_kernel<<<N_, F_, 0, stream>>>(ent, went, proj);
    scatter_kernel<<<4096, 256, 0, stream>>>(esrc, edst, eval_, alpha, proj, out);
}

// Round 3
// 532.487 us; speedup vs baseline: 1.3014x; 1.3014x over previous
//
#include <hip/hip_runtime.h>

#define R_ 8
#define N_ 40000
#define F_ 128
#define E_ 160000
#define NE (R_ * E_)   // 1,280,000 edges total

// --- K1: alpha[r] = sigmoid(tanh(rel @ w1 + b1) @ w2); also copy rel_mat to out tail ---
__global__ void alpha_and_rel_kernel(const float* __restrict__ rel,
                                     const float* __restrict__ w1,
                                     const float* __restrict__ b1,
                                     const float* __restrict__ w2,
                                     float* __restrict__ alpha,
                                     float* __restrict__ out_tail) {
    int r = blockIdx.x;          // 0..7
    int o = threadIdx.x;         // 0..127
    __shared__ float relrow[F_];
    __shared__ float red[F_];
    float rv = rel[r * F_ + o];
    relrow[o] = rv;
    out_tail[r * F_ + o] = rv;   // output[1] = rel_mat passthrough
    __syncthreads();
    float s = 0.f;
#pragma unroll 8
    for (int f = 0; f < F_; ++f)
        s += relrow[f] * w1[f * F_ + o];
    float h = tanhf(s + b1[o]);
    red[o] = h * w2[o];
    __syncthreads();
    for (int off = 64; off > 0; off >>= 1) {
        if (o < off) red[o] += red[o + off];
        __syncthreads();
    }
    if (o == 0) alpha[r] = 1.f / (1.f + expf(-red[0]));
}

// --- K2: proj = ent_mat @ weight_ent (N x F fp32) ---
__global__ void proj_kernel(const float* __restrict__ ent,
                            const float* __restrict__ W,
                            float* __restrict__ proj) {
    int n = blockIdx.x;
    int o = threadIdx.x;
    __shared__ float row[F_];
    row[o] = ent[n * F_ + o];
    __syncthreads();
    float s = 0.f;
#pragma unroll 8
    for (int f = 0; f < F_; ++f)
        s += row[f] * W[f * F_ + o];
    proj[n * F_ + o] = s;
}

// --- K3: histogram of src ---
__global__ void hist_kernel(const int* __restrict__ esrc, int* __restrict__ cnt) {
    int e = blockIdx.x * blockDim.x + threadIdx.x;
    if (e < NE) atomicAdd(&cnt[esrc[e]], 1);
}

// --- K4: exclusive scan of cnt -> row_ptr (and cursor copy), single block ---
__global__ void scan_kernel(const int* __restrict__ cnt, int* __restrict__ row_ptr,
                            int* __restrict__ cursor) {
    __shared__ int part[1024];
    const int CH = 40;                 // 1024*40 = 40960 >= N_
    int t = threadIdx.x;
    int lo = t * CH;
    int s = 0;
    for (int i = 0; i < CH; ++i) {
        int idx = lo + i;
        if (idx < N_) s += cnt[idx];
    }
    part[t] = s;
    __syncthreads();
    for (int off = 1; off < 1024; off <<= 1) {
        int v = (t >= off) ? part[t - off] : 0;
        __syncthreads();
        part[t] += v;
        __syncthreads();
    }
    int base = (t == 0) ? 0 : part[t - 1];
    for (int i = 0; i < CH; ++i) {
        int idx = lo + i;
        if (idx < N_) {
            row_ptr[idx] = base;
            cursor[idx]  = base;
            base += cnt[idx];
        }
    }
    if (t == 0) row_ptr[N_] = NE;
}

// --- K5: scatter edges into CSR order: sorted[pos] = (dst, alpha_r*val) ---
__global__ void fill_kernel(const int* __restrict__ esrc,
                            const int* __restrict__ edst,
                            const float* __restrict__ eval_,
                            const float* __restrict__ alpha,
                            int* __restrict__ cursor,
                            int2* __restrict__ sorted) {
    int e = blockIdx.x * blockDim.x + threadIdx.x;
    if (e >= NE) return;
    int r = e / E_;                    // const-div -> magic mul
    float w = alpha[r] * eval_[e];
    int s = esrc[e];
    int pos = atomicAdd(&cursor[s], 1);
    sorted[pos] = make_int2(edst[e], __float_as_int(w));
}

// --- K6: CSR SpMM, one wave per row, atomic-free. Writes every output row. ---
__global__ void spmm_kernel(const int* __restrict__ row_ptr,
                            const int2* __restrict__ sorted,
                            const float* __restrict__ proj,
                            float* __restrict__ out) {
    int wave = (blockIdx.x * blockDim.x + threadIdx.x) >> 6;
    int lane = threadIdx.x & 63;
    if (wave >= N_) return;
    int beg = row_ptr[wave];
    int end = row_ptr[wave + 1];
    float accx = 0.f, accy = 0.f;
    for (int j = beg; j < end; ++j) {
        int2 ed = sorted[j];                               // uniform across wave
        float w = __int_as_float(ed.y);
        const float2 p = *(const float2*)&proj[(size_t)ed.x * F_ + 2 * lane];
        accx += w * p.x;
        accy += w * p.y;
    }
    float2 o2 = make_float2(accx, accy);
    *(float2*)&out[(size_t)wave * F_ + 2 * lane] = o2;
}

extern "C" void kernel_launch(void* const* d_in, const int* in_sizes, int n_in,
                              void* d_out, int out_size, void* d_ws, size_t ws_size,
                              hipStream_t stream) {
    const float* ent   = (const float*)d_in[0];
    const float* rel   = (const float*)d_in[1];
    const int*   esrc  = (const int*)d_in[2];
    const int*   edst  = (const int*)d_in[3];
    const float* eval_ = (const float*)d_in[4];
    const float* went  = (const float*)d_in[5];
    const float* w1    = (const float*)d_in[6];
    const float* b1    = (const float*)d_in[7];
    const float* w2    = (const float*)d_in[8];

    float* out      = (float*)d_out;
    float* out_tail = out + (size_t)N_ * F_;   // rel_mat passthrough (R*F)

    // ws layout (256B-aligned chunks)
    char* ws = (char*)d_ws;
    size_t off = 0;
    float* proj   = (float*)(ws + off); off += (size_t)N_ * F_ * 4;        // 20.48 MB
    float* alpha  = (float*)(ws + off); off += 256;
    int*   cnt    = (int*)(ws + off);   off += (size_t)N_ * 4;             // 160 KB
    int*   rowptr = (int*)(ws + off);   off += (size_t)(N_ + 64) * 4;      // 160 KB
    int*   cursor = (int*)(ws + off);   off += (size_t)N_ * 4;             // 160 KB
    int2*  sorted = (int2*)(ws + off);  off += (size_t)NE * 8;             // 10.24 MB

    hipMemsetAsync(cnt, 0, (size_t)N_ * 4, stream);
    alpha_and_rel_kernel<<<R_, F_, 0, stream>>>(rel, w1, b1, w2, alpha, out_tail);
    proj_kernel<<<N_, F_, 0, stream>>>(ent, went, proj);
    hist_kernel<<<(NE + 255) / 256, 256, 0, stream>>>(esrc, cnt);
    scan_kernel<<<1, 1024, 0, stream>>>(cnt, rowptr, cursor);
    fill_kernel<<<(NE + 255) / 256, 256, 0, stream>>>(esrc, edst, eval_, alpha, cursor, sorted);
    spmm_kernel<<<(N_ * 64 + 255) / 256, 256, 0, stream>>>(rowptr, sorted, proj, out);
}

// Round 4
// 477.140 us; speedup vs baseline: 1.4524x; 1.1160x over previous
//
#include <hip/hip_runtime.h>

#define R_ 8
#define N_ 40000
#define F_ 128
#define E_ 160000
#define NE (R_ * E_)   // 1,280,000 edges

typedef unsigned short ushort;

// fp32 -> bf16 round-to-nearest-even (bit trick, no NaN care needed here)
__device__ __forceinline__ ushort f2bf(float x) {
    unsigned int u = __float_as_uint(x);
    return (ushort)((u + 0x7fffu + ((u >> 16) & 1u)) >> 16);
}

// --- K1: proj = ent @ W, 64 rows/block, thread = 8 rows x 4 cols, bf16 out ---
__global__ __launch_bounds__(256) void proj_tiled(const float* __restrict__ ent,
                                                  const float* __restrict__ W,
                                                  ushort* __restrict__ proj) {
    __shared__ float rows[64][F_];              // 32 KB
    const int t = threadIdx.x;
    const int row0 = blockIdx.x * 64;
    // stage 64 rows (8192 floats) via float4: 8 per thread, coalesced
    const float4* src = (const float4*)(ent + (size_t)row0 * F_);
    float4* dst = (float4*)rows;
#pragma unroll
    for (int i = 0; i < 8; ++i) dst[t + 256 * i] = src[t + 256 * i];
    __syncthreads();

    const int c4 = (t & 31) * 4;                // 4 consecutive cols
    const int r0 = (t >> 5) * 8;                // 8 consecutive rows
    float acc[8][4] = {};
    for (int f = 0; f < F_; f += 2) {
        float4 w0 = *(const float4*)&W[f * F_ + c4];
        float4 w1 = *(const float4*)&W[(f + 1) * F_ + c4];
#pragma unroll
        for (int i = 0; i < 8; ++i) {
            float2 rv = *(const float2*)&rows[r0 + i][f];   // ds_read_b64, broadcast
            acc[i][0] += rv.x * w0.x + rv.y * w1.x;
            acc[i][1] += rv.x * w0.y + rv.y * w1.y;
            acc[i][2] += rv.x * w0.z + rv.y * w1.z;
            acc[i][3] += rv.x * w0.w + rv.y * w1.w;
        }
    }
#pragma unroll
    for (int i = 0; i < 8; ++i) {
        ushort4 pk;
        pk.x = f2bf(acc[i][0]); pk.y = f2bf(acc[i][1]);
        pk.z = f2bf(acc[i][2]); pk.w = f2bf(acc[i][3]);
        *(ushort4*)&proj[(size_t)(row0 + r0 + i) * F_ + c4] = pk;
    }
}

// --- K2: histogram of src (+ rel_mat passthrough piggyback) ---
__global__ void hist_kernel(const int* __restrict__ esrc, int* __restrict__ cnt,
                            const float* __restrict__ rel, float* __restrict__ out_tail) {
    int e = blockIdx.x * blockDim.x + threadIdx.x;
    if (e < R_ * F_) out_tail[e] = rel[e];
    if (e < NE) atomicAdd(&cnt[esrc[e]], 1);
}

// --- K3: single-block: alpha MLP + exclusive scan cnt -> row_ptr/cursor ---
__global__ __launch_bounds__(1024) void scan_alpha_kernel(const int* __restrict__ cnt,
                                                          int* __restrict__ row_ptr,
                                                          int* __restrict__ cursor,
                                                          const float* __restrict__ rel,
                                                          const float* __restrict__ w1,
                                                          const float* __restrict__ b1,
                                                          const float* __restrict__ w2,
                                                          float* __restrict__ alpha) {
    __shared__ int part[1024];
    __shared__ float red[1024];
    const int t = threadIdx.x;
    // ---- alpha: t = r*128 + o, all 1024 threads active (R_=8, F_=128) ----
    {
        int r = t >> 7, o = t & 127;
        float s = 0.f;
#pragma unroll 8
        for (int f = 0; f < F_; ++f)
            s += rel[r * F_ + f] * w1[f * F_ + o];
        float h = tanhf(s + b1[o]);
        red[t] = h * w2[o];
        __syncthreads();
        for (int off = 64; off > 0; off >>= 1) {
            if ((t & 127) < off) red[t] += red[t + off];
            __syncthreads();
        }
        if ((t & 127) == 0) alpha[r] = 1.f / (1.f + expf(-red[t]));
        __syncthreads();
    }
    // ---- exclusive scan over N_ counts, CH=40 per thread ----
    const int CH = 40;
    int lo = t * CH;
    int s = 0;
    for (int i = 0; i < CH; ++i) {
        int idx = lo + i;
        if (idx < N_) s += cnt[idx];
    }
    part[t] = s;
    __syncthreads();
    for (int off = 1; off < 1024; off <<= 1) {
        int v = (t >= off) ? part[t - off] : 0;
        __syncthreads();
        part[t] += v;
        __syncthreads();
    }
    int base = (t == 0) ? 0 : part[t - 1];
    for (int i = 0; i < CH; ++i) {
        int idx = lo + i;
        if (idx < N_) {
            row_ptr[idx] = base;
            cursor[idx]  = base;
            base += cnt[idx];
        }
    }
    if (t == 0) row_ptr[N_] = NE;
}

// --- K4: scatter edges into CSR order: sorted[pos] = (dst, alpha_r*val) ---
__global__ void fill_kernel(const int* __restrict__ esrc,
                            const int* __restrict__ edst,
                            const float* __restrict__ eval_,
                            const float* __restrict__ alpha,
                            int* __restrict__ cursor,
                            int2* __restrict__ sorted) {
    int e = blockIdx.x * blockDim.x + threadIdx.x;
    if (e >= NE) return;
    int r = e / E_;                    // const-div -> magic mul
    float w = alpha[r] * eval_[e];
    int s = esrc[e];
    int pos = atomicAdd(&cursor[s], 1);
    sorted[pos] = make_int2(edst[e], __float_as_int(w));
}

// --- K5: CSR SpMM, one wave per row, bf16 gathers, fp32 accum, atomic-free ---
__global__ __launch_bounds__(256) void spmm_kernel(const int* __restrict__ row_ptr,
                                                   const int2* __restrict__ sorted,
                                                   const ushort* __restrict__ proj,
                                                   float* __restrict__ out) {
    int wave = (blockIdx.x * blockDim.x + threadIdx.x) >> 6;
    int lane = threadIdx.x & 63;
    if (wave >= N_) return;
    int beg = row_ptr[wave];
    int end = row_ptr[wave + 1];
    float accx = 0.f, accy = 0.f;
    for (int j = beg; j < end; ++j) {
        int2 ed = sorted[j];                                   // wave-uniform
        float w = __int_as_float(ed.y);
        unsigned int u = *(const unsigned int*)&proj[(size_t)ed.x * F_ + 2 * lane];
        accx += w * __uint_as_float(u << 16);                  // low bf16 -> col 2*lane
        accy += w * __uint_as_float(u & 0xffff0000u);          // high bf16 -> col 2*lane+1
    }
    *(float2*)&out[(size_t)wave * F_ + 2 * lane] = make_float2(accx, accy);
}

extern "C" void kernel_launch(void* const* d_in, const int* in_sizes, int n_in,
                              void* d_out, int out_size, void* d_ws, size_t ws_size,
                              hipStream_t stream) {
    const float* ent   = (const float*)d_in[0];
    const float* rel   = (const float*)d_in[1];
    const int*   esrc  = (const int*)d_in[2];
    const int*   edst  = (const int*)d_in[3];
    const float* eval_ = (const float*)d_in[4];
    const float* went  = (const float*)d_in[5];
    const float* w1    = (const float*)d_in[6];
    const float* b1    = (const float*)d_in[7];
    const float* w2    = (const float*)d_in[8];

    float* out      = (float*)d_out;
    float* out_tail = out + (size_t)N_ * F_;   // rel_mat passthrough (R*F)

    char* ws = (char*)d_ws;
    size_t off = 0;
    ushort* proj  = (ushort*)(ws + off); off += (size_t)N_ * F_ * 2;   // 10.24 MB bf16
    float* alpha  = (float*)(ws + off);  off += 256;
    int*   cnt    = (int*)(ws + off);    off += (size_t)N_ * 4;        // 160 KB
    int*   rowptr = (int*)(ws + off);    off += (size_t)(N_ + 64) * 4; // 160 KB
    int*   cursor = (int*)(ws + off);    off += (size_t)N_ * 4;        // 160 KB
    int2*  sorted = (int2*)(ws + off);   off += (size_t)NE * 8;        // 10.24 MB

    hipMemsetAsync(cnt, 0, (size_t)N_ * 4, stream);
    proj_tiled<<<N_ / 64, 256, 0, stream>>>(ent, went, proj);
    hist_kernel<<<(NE + 255) / 256, 256, 0, stream>>>(esrc, cnt, rel, out_tail);
    scan_alpha_kernel<<<1, 1024, 0, stream>>>(cnt, rowptr, cursor, rel, w1, b1, w2, alpha);
    fill_kernel<<<(NE + 255) / 256, 256, 0, stream>>>(esrc, edst, eval_, alpha, cursor, sorted);
    spmm_kernel<<<(N_ * 64) / 256, 256, 0, stream>>>(rowptr, sorted, proj, out);
}

// Round 5
// 296.783 us; speedup vs baseline: 2.3350x; 1.6077x over previous
//
#include <hip/hip_runtime.h>

#define R_ 8
#define N_ 40000
#define F_ 128
#define E_ 160000
#define NE (R_ * E_)   // 1,280,000 edges
#define NB 40          // scan chunks of 1024 (40*1024 = 40960 >= N_)

typedef unsigned short ushort;
typedef unsigned int uint;

// fp32 -> bf16 round-to-nearest-even
__device__ __forceinline__ ushort f2bf(float x) {
    uint u = __float_as_uint(x);
    return (ushort)((u + 0x7fffu + ((u >> 16) & 1u)) >> 16);
}

// --- K1: fused independent prep ---
// blocks [0,625):    proj = ent @ W  (64 rows/block, bf16 out)
// blocks [625,1875): histogram of esrc (4 edges/thread)
// block  1875:       rel_mat passthrough to out tail
// blocks [1876,1880): alpha MLP (2 relations/block)
__global__ __launch_bounds__(256) void fused_prep(
        const float* __restrict__ ent, const float* __restrict__ W,
        ushort* __restrict__ proj,
        const int* __restrict__ esrc, int* __restrict__ cnt,
        const float* __restrict__ rel, float* __restrict__ out_tail,
        const float* __restrict__ w1, const float* __restrict__ b1,
        const float* __restrict__ w2, float* __restrict__ alpha) {
    __shared__ float smem[64 * F_];          // 32 KB (proj); alpha uses first 256
    const int t = threadIdx.x;
    const int b = blockIdx.x;
    if (b < 625) {
        const int row0 = b * 64;
        const float4* src = (const float4*)(ent + (size_t)row0 * F_);
        float4* dst4 = (float4*)smem;
#pragma unroll
        for (int i = 0; i < 8; ++i) dst4[t + 256 * i] = src[t + 256 * i];
        __syncthreads();
        const int c4 = (t & 31) * 4;         // 4 consecutive cols
        const int r0 = (t >> 5) * 8;         // 8 consecutive rows
        float acc[8][4] = {};
        for (int f = 0; f < F_; f += 2) {
            float4 w0 = *(const float4*)&W[f * F_ + c4];
            float4 wn = *(const float4*)&W[(f + 1) * F_ + c4];
#pragma unroll
            for (int i = 0; i < 8; ++i) {
                float2 rv = *(const float2*)&smem[(r0 + i) * F_ + f];
                acc[i][0] += rv.x * w0.x + rv.y * wn.x;
                acc[i][1] += rv.x * w0.y + rv.y * wn.y;
                acc[i][2] += rv.x * w0.z + rv.y * wn.z;
                acc[i][3] += rv.x * w0.w + rv.y * wn.w;
            }
        }
#pragma unroll
        for (int i = 0; i < 8; ++i) {
            ushort4 pk;
            pk.x = f2bf(acc[i][0]); pk.y = f2bf(acc[i][1]);
            pk.z = f2bf(acc[i][2]); pk.w = f2bf(acc[i][3]);
            *(ushort4*)&proj[(size_t)(row0 + r0 + i) * F_ + c4] = pk;
        }
    } else if (b < 1875) {
        int hb = b - 625;
        int4 s4 = ((const int4*)esrc)[hb * 256 + t];
        atomicAdd(&cnt[s4.x], 1); atomicAdd(&cnt[s4.y], 1);
        atomicAdd(&cnt[s4.z], 1); atomicAdd(&cnt[s4.w], 1);
    } else if (b == 1875) {
        ((float4*)out_tail)[t] = ((const float4*)rel)[t];   // 1024 floats
    } else {
        int r = (b - 1876) * 2 + (t >> 7);
        int o = t & 127;
        float s = 0.f;
#pragma unroll 8
        for (int f = 0; f < F_; ++f) s += rel[r * F_ + f] * w1[f * F_ + o];
        float h = tanhf(s + b1[o]);
        smem[t] = h * w2[o];
        __syncthreads();
        for (int off = 64; off > 0; off >>= 1) {
            if ((t & 127) < off) smem[t] += smem[t + off];
            __syncthreads();
        }
        if ((t & 127) == 0) alpha[r] = 1.f / (1.f + expf(-smem[t]));
    }
}

// --- K2: per-chunk partial sums (1024 counts per block) ---
__global__ __launch_bounds__(256) void partial_kernel(const int* __restrict__ cnt,
                                                      int* __restrict__ partial) {
    __shared__ int red[256];
    int b = blockIdx.x, t = threadIdx.x;
    int4 c = ((const int4*)cnt)[b * 256 + t];
    red[t] = c.x + c.y + c.z + c.w;
    __syncthreads();
    for (int off = 128; off > 0; off >>= 1) {
        if (t < off) red[t] += red[t + off];
        __syncthreads();
    }
    if (t == 0) partial[b] = red[0];
}

// --- K3: scan the 40 chunk partials (trivial serial on one lane) ---
__global__ void scanp_kernel(const int* __restrict__ partial, int* __restrict__ chunkbase,
                             int* __restrict__ rowptr) {
    if (threadIdx.x == 0) {
        int s = 0;
        for (int i = 0; i < NB; ++i) { chunkbase[i] = s; s += partial[i]; }
        rowptr[N_] = NE;
    }
}

// --- K4: per-chunk exclusive scan -> rowptr + cursor ---
__global__ __launch_bounds__(256) void emit_kernel(const int* __restrict__ cnt,
                                                   const int* __restrict__ chunkbase,
                                                   int* __restrict__ rowptr,
                                                   int* __restrict__ cursor) {
    __shared__ int ps[256];
    int b = blockIdx.x, t = threadIdx.x;
    int4 c = ((const int4*)cnt)[b * 256 + t];
    ps[t] = c.x + c.y + c.z + c.w;
    __syncthreads();
    for (int off = 1; off < 256; off <<= 1) {
        int v = (t >= off) ? ps[t - off] : 0;
        __syncthreads();
        ps[t] += v;
        __syncthreads();
    }
    int base = chunkbase[b] + (t ? ps[t - 1] : 0);
    int idx0 = b * 1024 + t * 4;
    if (idx0 < N_) {          // N_ % 4 == 0, so all-or-none per int4
        int4 e = make_int4(base, base + c.x, base + c.x + c.y, base + c.x + c.y + c.z);
        ((int4*)rowptr)[idx0 >> 2] = e;
        ((int4*)cursor)[idx0 >> 2] = e;
    }
}

// --- K5: scatter edges into CSR order, packed 4B entries (dst | bf16(w)<<16) ---
__global__ __launch_bounds__(256) void fill_kernel(const int* __restrict__ esrc,
                                                   const int* __restrict__ edst,
                                                   const float* __restrict__ eval_,
                                                   const float* __restrict__ alpha,
                                                   int* __restrict__ cursor,
                                                   uint* __restrict__ sorted) {
    int i = blockIdx.x * 256 + threadIdx.x;
    int4 s4 = ((const int4*)esrc)[i];
    int4 d4 = ((const int4*)edst)[i];
    float4 v4 = ((const float4*)eval_)[i];
    float a = alpha[(i * 4) / E_];            // E_ % 4 == 0: all 4 in same relation
    uint t0 = (uint)d4.x | ((uint)f2bf(a * v4.x) << 16);
    uint t1 = (uint)d4.y | ((uint)f2bf(a * v4.y) << 16);
    uint t2 = (uint)d4.z | ((uint)f2bf(a * v4.z) << 16);
    uint t3 = (uint)d4.w | ((uint)f2bf(a * v4.w) << 16);
    sorted[atomicAdd(&cursor[s4.x], 1)] = t0;
    sorted[atomicAdd(&cursor[s4.y], 1)] = t1;
    sorted[atomicAdd(&cursor[s4.z], 1)] = t2;
    sorted[atomicAdd(&cursor[s4.w], 1)] = t3;
}

// --- K6: CSR SpMM, wave/row, unroll-4 gathers, bf16 proj, fp32 accum ---
__global__ __launch_bounds__(256) void spmm_kernel(const int* __restrict__ rowptr,
                                                   const uint* __restrict__ sorted,
                                                   const ushort* __restrict__ proj,
                                                   float* __restrict__ out) {
    int wave = (blockIdx.x * 256 + threadIdx.x) >> 6;
    int lane = threadIdx.x & 63;
    int beg = __builtin_amdgcn_readfirstlane(rowptr[wave]);
    int end = __builtin_amdgcn_readfirstlane(rowptr[wave + 1]);
    float accx = 0.f, accy = 0.f;
    int j = beg;
    for (; j + 4 <= end; j += 4) {
        uint e0 = sorted[j], e1 = sorted[j + 1], e2 = sorted[j + 2], e3 = sorted[j + 3];
        uint u0 = *(const uint*)&proj[((e0 & 0xffffu) << 7) + 2 * lane];
        uint u1 = *(const uint*)&proj[((e1 & 0xffffu) << 7) + 2 * lane];
        uint u2 = *(const uint*)&proj[((e2 & 0xffffu) << 7) + 2 * lane];
        uint u3 = *(const uint*)&proj[((e3 & 0xffffu) << 7) + 2 * lane];
        float w0 = __uint_as_float(e0 & 0xffff0000u);
        float w1 = __uint_as_float(e1 & 0xffff0000u);
        float w2 = __uint_as_float(e2 & 0xffff0000u);
        float w3 = __uint_as_float(e3 & 0xffff0000u);
        accx += w0 * __uint_as_float(u0 << 16);
        accy += w0 * __uint_as_float(u0 & 0xffff0000u);
        accx += w1 * __uint_as_float(u1 << 16);
        accy += w1 * __uint_as_float(u1 & 0xffff0000u);
        accx += w2 * __uint_as_float(u2 << 16);
        accy += w2 * __uint_as_float(u2 & 0xffff0000u);
        accx += w3 * __uint_as_float(u3 << 16);
        accy += w3 * __uint_as_float(u3 & 0xffff0000u);
    }
    for (; j < end; ++j) {
        uint e = sorted[j];
        uint u = *(const uint*)&proj[((e & 0xffffu) << 7) + 2 * lane];
        float w = __uint_as_float(e & 0xffff0000u);
        accx += w * __uint_as_float(u << 16);
        accy += w * __uint_as_float(u & 0xffff0000u);
    }
    *(float2*)&out[((size_t)wave << 7) + 2 * lane] = make_float2(accx, accy);
}

extern "C" void kernel_launch(void* const* d_in, const int* in_sizes, int n_in,
                              void* d_out, int out_size, void* d_ws, size_t ws_size,
                              hipStream_t stream) {
    const float* ent   = (const float*)d_in[0];
    const float* rel   = (const float*)d_in[1];
    const int*   esrc  = (const int*)d_in[2];
    const int*   edst  = (const int*)d_in[3];
    const float* eval_ = (const float*)d_in[4];
    const float* went  = (const float*)d_in[5];
    const float* w1    = (const float*)d_in[6];
    const float* b1    = (const float*)d_in[7];
    const float* w2    = (const float*)d_in[8];

    float* out      = (float*)d_out;
    float* out_tail = out + (size_t)N_ * F_;

    char* ws = (char*)d_ws;
    size_t off = 0;
    ushort* proj    = (ushort*)(ws + off); off += (size_t)N_ * F_ * 2;    // 10.24 MB
    float* alpha    = (float*)(ws + off);  off += 256;
    int*   cnt      = (int*)(ws + off);    off += (size_t)NB * 1024 * 4;  // 163.84 KB
    int*   rowptr   = (int*)(ws + off);    off += (size_t)(N_ + 64) * 4;
    int*   cursor   = (int*)(ws + off);    off += (size_t)N_ * 4;
    uint*  sorted   = (uint*)(ws + off);   off += (size_t)NE * 4;         // 5.12 MB
    int*   partial  = (int*)(ws + off);    off += 256;
    int*   chunkb   = (int*)(ws + off);    off += 256;

    hipMemsetAsync(cnt, 0, (size_t)NB * 1024 * 4, stream);   // zero padded counts
    fused_prep<<<1880, 256, 0, stream>>>(ent, went, proj, esrc, cnt,
                                         rel, out_tail, w1, b1, w2, alpha);
    partial_kernel<<<NB, 256, 0, stream>>>(cnt, partial);
    scanp_kernel<<<1, 64, 0, stream>>>(partial, chunkb, rowptr);
    emit_kernel<<<NB, 256, 0, stream>>>(cnt, chunkb, rowptr, cursor);
    fill_kernel<<<NE / 1024, 256, 0, stream>>>(esrc, edst, eval_, alpha, cursor, sorted);
    spmm_kernel<<<(N_ * 64) / 256, 256, 0, stream>>>(rowptr, sorted, proj, out);
}

// Round 6
// 236.443 us; speedup vs baseline: 2.9309x; 1.2552x over previous
//
#include <hip/hip_runtime.h>

#define R_ 8
#define N_ 40000
#define F_ 128
#define E_ 160000
#define NE (R_ * E_)   // 1,280,000 edges
#define NB 40          // row-count scan chunks of 1024
#define NBUK 313       // src>>7 buckets (128 rows each), 313*128 = 40064 >= N_
#define FBLK 320       // edge chunks
#define FCHUNK 4000    // FBLK * FCHUNK == NE exactly

typedef unsigned short ushort;
typedef unsigned int uint;

// fp32 -> bf16 round-to-nearest-even
__device__ __forceinline__ ushort f2bf(float x) {
    uint u = __float_as_uint(x);
    return (ushort)((u + 0x7fffu + ((u >> 16) & 1u)) >> 16);
}

// --- K1: fused independent prep ---
// blocks [0,625):      proj = ent @ W  (64 rows/block, bf16 out)
// blocks [625,1875):   row histogram of esrc (4 edges/thread)
// block  1875:         rel_mat passthrough to out tail
// blocks [1876,1880):  alpha MLP (2 relations/block)
// blocks [1880,2200):  fillA — per-chunk bucket histogram (313 buckets)
__global__ __launch_bounds__(256) void fused_prep(
        const float* __restrict__ ent, const float* __restrict__ W,
        ushort* __restrict__ proj,
        const int* __restrict__ esrc, int* __restrict__ cnt,
        const float* __restrict__ rel, float* __restrict__ out_tail,
        const float* __restrict__ w1, const float* __restrict__ b1,
        const float* __restrict__ w2, float* __restrict__ alpha,
        int* __restrict__ hist) {
    __shared__ float smem[64 * F_];          // 32 KB; reused as int[] by fillA
    const int t = threadIdx.x;
    const int b = blockIdx.x;
    if (b < 625) {
        const int row0 = b * 64;
        const float4* src = (const float4*)(ent + (size_t)row0 * F_);
        float4* dst4 = (float4*)smem;
#pragma unroll
        for (int i = 0; i < 8; ++i) dst4[t + 256 * i] = src[t + 256 * i];
        __syncthreads();
        const int c4 = (t & 31) * 4;
        const int r0 = (t >> 5) * 8;
        float acc[8][4] = {};
        for (int f = 0; f < F_; f += 2) {
            float4 w0 = *(const float4*)&W[f * F_ + c4];
            float4 wn = *(const float4*)&W[(f + 1) * F_ + c4];
#pragma unroll
            for (int i = 0; i < 8; ++i) {
                float2 rv = *(const float2*)&smem[(r0 + i) * F_ + f];
                acc[i][0] += rv.x * w0.x + rv.y * wn.x;
                acc[i][1] += rv.x * w0.y + rv.y * wn.y;
                acc[i][2] += rv.x * w0.z + rv.y * wn.z;
                acc[i][3] += rv.x * w0.w + rv.y * wn.w;
            }
        }
#pragma unroll
        for (int i = 0; i < 8; ++i) {
            ushort4 pk;
            pk.x = f2bf(acc[i][0]); pk.y = f2bf(acc[i][1]);
            pk.z = f2bf(acc[i][2]); pk.w = f2bf(acc[i][3]);
            *(ushort4*)&proj[(size_t)(row0 + r0 + i) * F_ + c4] = pk;
        }
    } else if (b < 1875) {
        int hb = b - 625;
        int4 s4 = ((const int4*)esrc)[hb * 256 + t];
        atomicAdd(&cnt[s4.x], 1); atomicAdd(&cnt[s4.y], 1);
        atomicAdd(&cnt[s4.z], 1); atomicAdd(&cnt[s4.w], 1);
    } else if (b == 1875) {
        ((float4*)out_tail)[t] = ((const float4*)rel)[t];   // 1024 floats
    } else if (b < 1880) {
        int r = (b - 1876) * 2 + (t >> 7);
        int o = t & 127;
        float s = 0.f;
#pragma unroll 8
        for (int f = 0; f < F_; ++f) s += rel[r * F_ + f] * w1[f * F_ + o];
        float h = tanhf(s + b1[o]);
        smem[t] = h * w2[o];
        __syncthreads();
        for (int off = 64; off > 0; off >>= 1) {
            if ((t & 127) < off) smem[t] += smem[t + off];
            __syncthreads();
        }
        if ((t & 127) == 0) alpha[r] = 1.f / (1.f + expf(-smem[t]));
    } else {
        // fillA: bucket histogram for chunk hb
        int hb = b - 1880;
        int* h = (int*)smem;
        for (int i = t; i < NBUK; i += 256) h[i] = 0;
        __syncthreads();
        int base = hb * FCHUNK;
        for (int i = t; i < FCHUNK; i += 256)
            atomicAdd(&h[esrc[base + i] >> 7], 1);
        __syncthreads();
        for (int i = t; i < NBUK; i += 256) hist[hb * NBUK + i] = h[i];
    }
}

// --- K2: per-chunk partial sums of row counts ---
__global__ __launch_bounds__(256) void partial_kernel(const int* __restrict__ cnt,
                                                      int* __restrict__ partial) {
    __shared__ int red[256];
    int b = blockIdx.x, t = threadIdx.x;
    int4 c = ((const int4*)cnt)[b * 256 + t];
    red[t] = c.x + c.y + c.z + c.w;
    __syncthreads();
    for (int off = 128; off > 0; off >>= 1) {
        if (t < off) red[t] += red[t + off];
        __syncthreads();
    }
    if (t == 0) partial[b] = red[0];
}

// --- K3: scan the 40 chunk partials ---
__global__ void scanp_kernel(const int* __restrict__ partial, int* __restrict__ chunkbase,
                             int* __restrict__ rowptr) {
    if (threadIdx.x == 0) {
        int s = 0;
        for (int i = 0; i < NB; ++i) { chunkbase[i] = s; s += partial[i]; }
        rowptr[N_] = NE;
    }
}

// --- K4: per-chunk exclusive scan -> rowptr ---
__global__ __launch_bounds__(256) void emit_kernel(const int* __restrict__ cnt,
                                                   const int* __restrict__ chunkbase,
                                                   int* __restrict__ rowptr) {
    __shared__ int ps[256];
    int b = blockIdx.x, t = threadIdx.x;
    int4 c = ((const int4*)cnt)[b * 256 + t];
    ps[t] = c.x + c.y + c.z + c.w;
    __syncthreads();
    for (int off = 1; off < 256; off <<= 1) {
        int v = (t >= off) ? ps[t - off] : 0;
        __syncthreads();
        ps[t] += v;
        __syncthreads();
    }
    int base = chunkbase[b] + (t ? ps[t - 1] : 0);
    int idx0 = b * 1024 + t * 4;
    if (idx0 < N_) {
        int4 e = make_int4(base, base + c.x, base + c.x + c.y, base + c.x + c.y + c.z);
        ((int4*)rowptr)[idx0 >> 2] = e;
    }
}

// --- K5: per bucket, exclusive-scan the FBLK chunk counts -> blockbase ---
__global__ __launch_bounds__(FBLK) void fillscan_kernel(const int* __restrict__ hist,
                                                        const int* __restrict__ rowptr,
                                                        int* __restrict__ blockbase) {
    __shared__ int sc[FBLK];
    int b = blockIdx.x, t = threadIdx.x;
    int own = hist[t * NBUK + b];
    sc[t] = own;
    __syncthreads();
    for (int off = 1; off < FBLK; off <<= 1) {
        int v = (t >= off) ? sc[t - off] : 0;
        __syncthreads();
        sc[t] += v;
        __syncthreads();
    }
    blockbase[b * FBLK + t] = rowptr[b << 7] + sc[t] - own;   // exclusive
}

// --- K6: fillB — stage edges bucket-ordered with contiguous per-(chunk,bucket) runs ---
__global__ __launch_bounds__(256) void fillB_kernel(const int* __restrict__ esrc,
                                                    const int* __restrict__ edst,
                                                    const float* __restrict__ eval_,
                                                    const float* __restrict__ alpha,
                                                    const int* __restrict__ blockbase,
                                                    uint2* __restrict__ staged) {
    __shared__ int lcnt[NBUK];
    __shared__ int lbase[NBUK];
    int t = threadIdx.x, blk = blockIdx.x;
    for (int i = t; i < NBUK; i += 256) {
        lcnt[i] = 0;
        lbase[i] = blockbase[i * FBLK + blk];
    }
    __syncthreads();
    int base = blk * FCHUNK;
    for (int i = t; i < FCHUNK; i += 256) {
        int e = base + i;
        int s = esrc[e];
        int d = edst[e];
        float w = alpha[e / E_] * eval_[e];
        int bk = s >> 7;
        int rank = atomicAdd(&lcnt[bk], 1);
        staged[lbase[bk] + rank] = make_uint2((uint)d | ((uint)f2bf(w) << 16), (uint)s);
    }
}

// --- K7: fillC — within-bucket counting sort to exact CSR position ---
__global__ __launch_bounds__(256) void fillC_kernel(const uint2* __restrict__ staged,
                                                    const int* __restrict__ rowptr,
                                                    uint* __restrict__ sorted) {
    __shared__ int cur[128];
    int b = blockIdx.x, t = threadIdx.x;
    int row0 = b << 7;
    if (t < 128) cur[t] = rowptr[row0 + t];
    __syncthreads();
    int estart = rowptr[row0];
    int eend = rowptr[min(row0 + 128, N_)];
    for (int k = estart + t; k < eend; k += 256) {
        uint2 ed = staged[k];
        int pos = atomicAdd(&cur[ed.y & 127], 1);
        sorted[pos] = ed.x;     // writes confined to this bucket's ~16KB window
    }
}

// --- K8: CSR SpMM, wave/row, unroll-4 gathers, bf16 proj, fp32 accum ---
__global__ __launch_bounds__(256) void spmm_kernel(const int* __restrict__ rowptr,
                                                   const uint* __restrict__ sorted,
                                                   const ushort* __restrict__ proj,
                                                   float* __restrict__ out) {
    int wave = (blockIdx.x * 256 + threadIdx.x) >> 6;
    int lane = threadIdx.x & 63;
    int beg = __builtin_amdgcn_readfirstlane(rowptr[wave]);
    int end = __builtin_amdgcn_readfirstlane(rowptr[wave + 1]);
    float accx = 0.f, accy = 0.f;
    int j = beg;
    for (; j + 4 <= end; j += 4) {
        uint e0 = sorted[j], e1 = sorted[j + 1], e2 = sorted[j + 2], e3 = sorted[j + 3];
        uint u0 = *(const uint*)&proj[((e0 & 0xffffu) << 7) + 2 * lane];
        uint u1 = *(const uint*)&proj[((e1 & 0xffffu) << 7) + 2 * lane];
        uint u2 = *(const uint*)&proj[((e2 & 0xffffu) << 7) + 2 * lane];
        uint u3 = *(const uint*)&proj[((e3 & 0xffffu) << 7) + 2 * lane];
        float w0 = __uint_as_float(e0 & 0xffff0000u);
        float w1 = __uint_as_float(e1 & 0xffff0000u);
        float w2 = __uint_as_float(e2 & 0xffff0000u);
        float w3 = __uint_as_float(e3 & 0xffff0000u);
        accx += w0 * __uint_as_float(u0 << 16);
        accy += w0 * __uint_as_float(u0 & 0xffff0000u);
        accx += w1 * __uint_as_float(u1 << 16);
        accy += w1 * __uint_as_float(u1 & 0xffff0000u);
        accx += w2 * __uint_as_float(u2 << 16);
        accy += w2 * __uint_as_float(u2 & 0xffff0000u);
        accx += w3 * __uint_as_float(u3 << 16);
        accy += w3 * __uint_as_float(u3 & 0xffff0000u);
    }
    for (; j < end; ++j) {
        uint e = sorted[j];
        uint u = *(const uint*)&proj[((e & 0xffffu) << 7) + 2 * lane];
        float w = __uint_as_float(e & 0xffff0000u);
        accx += w * __uint_as_float(u << 16);
        accy += w * __uint_as_float(u & 0xffff0000u);
    }
    *(float2*)&out[((size_t)wave << 7) + 2 * lane] = make_float2(accx, accy);
}

extern "C" void kernel_launch(void* const* d_in, const int* in_sizes, int n_in,
                              void* d_out, int out_size, void* d_ws, size_t ws_size,
                              hipStream_t stream) {
    const float* ent   = (const float*)d_in[0];
    const float* rel   = (const float*)d_in[1];
    const int*   esrc  = (const int*)d_in[2];
    const int*   edst  = (const int*)d_in[3];
    const float* eval_ = (const float*)d_in[4];
    const float* went  = (const float*)d_in[5];
    const float* w1    = (const float*)d_in[6];
    const float* b1    = (const float*)d_in[7];
    const float* w2    = (const float*)d_in[8];

    float* out      = (float*)d_out;
    float* out_tail = out + (size_t)N_ * F_;

    char* ws = (char*)d_ws;
    size_t off = 0;
    ushort* proj     = (ushort*)(ws + off); off += (size_t)N_ * F_ * 2;     // 10.24 MB
    float* alpha     = (float*)(ws + off);  off += 256;
    int*   cnt       = (int*)(ws + off);    off += (size_t)NB * 1024 * 4;   // 160 KB
    int*   rowptr    = (int*)(ws + off);    off += (size_t)(N_ + 64) * 4;   // 160 KB
    uint*  sorted    = (uint*)(ws + off);   off += (size_t)NE * 4;          // 5.12 MB
    uint2* staged    = (uint2*)(ws + off);  off += (size_t)NE * 8;          // 10.24 MB
    int*   hist      = (int*)(ws + off);    off += (size_t)FBLK * NBUK * 4; // 400 KB
    int*   blockbase = (int*)(ws + off);    off += (size_t)NBUK * FBLK * 4; // 400 KB
    int*   partial   = (int*)(ws + off);    off += 256;
    int*   chunkb    = (int*)(ws + off);    off += 256;

    hipMemsetAsync(cnt, 0, (size_t)NB * 1024 * 4, stream);
    fused_prep<<<1880 + FBLK, 256, 0, stream>>>(ent, went, proj, esrc, cnt,
                                                rel, out_tail, w1, b1, w2, alpha, hist);
    partial_kernel<<<NB, 256, 0, stream>>>(cnt, partial);
    scanp_kernel<<<1, 64, 0, stream>>>(partial, chunkb, rowptr);
    emit_kernel<<<NB, 256, 0, stream>>>(cnt, chunkb, rowptr);
    fillscan_kernel<<<NBUK, FBLK, 0, stream>>>(hist, rowptr, blockbase);
    fillB_kernel<<<FBLK, 256, 0, stream>>>(esrc, edst, eval_, alpha, blockbase, staged);
    fillC_kernel<<<NBUK, 256, 0, stream>>>(staged, rowptr, sorted);
    spmm_kernel<<<(N_ * 64) / 256, 256, 0, stream>>>(rowptr, sorted, proj, out);
}

// Round 7
// 196.770 us; speedup vs baseline: 3.5219x; 1.2016x over previous
//
#include <hip/hip_runtime.h>

#define R_ 8
#define N_ 40000
#define F_ 128
#define E_ 160000
#define NE (R_ * E_)   // 1,280,000 edges
#define NBUK 313       // src>>7 buckets (128 rows each), 313*128 = 40064 >= N_
#define FBLK 320       // edge chunks
#define FCHUNK 4000    // FBLK * FCHUNK == NE exactly

typedef unsigned short ushort;
typedef unsigned int uint;

// fp32 -> bf16 round-to-nearest-even
__device__ __forceinline__ ushort f2bf(float x) {
    uint u = __float_as_uint(x);
    return (ushort)((u + 0x7fffu + ((u >> 16) & 1u)) >> 16);
}

// --- K1: fused independent prep ---
// blocks [0,625):    proj = ent @ W  (64 rows/block, bf16 out)
// block  625:        rel_mat passthrough to out tail
// blocks [626,630):  alpha MLP (2 relations/block)
// blocks [630,950):  fillA — per-chunk bucket histogram (313 buckets)
__global__ __launch_bounds__(256) void fused_prep(
        const float* __restrict__ ent, const float* __restrict__ W,
        ushort* __restrict__ proj,
        const int* __restrict__ esrc,
        const float* __restrict__ rel, float* __restrict__ out_tail,
        const float* __restrict__ w1, const float* __restrict__ b1,
        const float* __restrict__ w2, float* __restrict__ alpha,
        int* __restrict__ hist) {
    __shared__ float smem[64 * F_];          // 32 KB; reused as int[] by fillA
    const int t = threadIdx.x;
    const int b = blockIdx.x;
    if (b < 625) {
        const int row0 = b * 64;
        const float4* src = (const float4*)(ent + (size_t)row0 * F_);
        float4* dst4 = (float4*)smem;
#pragma unroll
        for (int i = 0; i < 8; ++i) dst4[t + 256 * i] = src[t + 256 * i];
        __syncthreads();
        const int c4 = (t & 31) * 4;
        const int r0 = (t >> 5) * 8;
        float acc[8][4] = {};
        for (int f = 0; f < F_; f += 2) {
            float4 w0 = *(const float4*)&W[f * F_ + c4];
            float4 wn = *(const float4*)&W[(f + 1) * F_ + c4];
#pragma unroll
            for (int i = 0; i < 8; ++i) {
                float2 rv = *(const float2*)&smem[(r0 + i) * F_ + f];
                acc[i][0] += rv.x * w0.x + rv.y * wn.x;
                acc[i][1] += rv.x * w0.y + rv.y * wn.y;
                acc[i][2] += rv.x * w0.z + rv.y * wn.z;
                acc[i][3] += rv.x * w0.w + rv.y * wn.w;
            }
        }
#pragma unroll
        for (int i = 0; i < 8; ++i) {
            ushort4 pk;
            pk.x = f2bf(acc[i][0]); pk.y = f2bf(acc[i][1]);
            pk.z = f2bf(acc[i][2]); pk.w = f2bf(acc[i][3]);
            *(ushort4*)&proj[(size_t)(row0 + r0 + i) * F_ + c4] = pk;
        }
    } else if (b == 625) {
        ((float4*)out_tail)[t] = ((const float4*)rel)[t];   // 1024 floats
    } else if (b < 630) {
        int r = (b - 626) * 2 + (t >> 7);
        int o = t & 127;
        float s = 0.f;
#pragma unroll 8
        for (int f = 0; f < F_; ++f) s += rel[r * F_ + f] * w1[f * F_ + o];
        float h = tanhf(s + b1[o]);
        smem[t] = h * w2[o];
        __syncthreads();
        for (int off = 64; off > 0; off >>= 1) {
            if ((t & 127) < off) smem[t] += smem[t + off];
            __syncthreads();
        }
        if ((t & 127) == 0) alpha[r] = 1.f / (1.f + expf(-smem[t]));
    } else {
        // fillA: bucket histogram for chunk hb
        int hb = b - 630;
        int* h = (int*)smem;
        for (int i = t; i < NBUK; i += 256) h[i] = 0;
        __syncthreads();
        int base = hb * FCHUNK;
        for (int i = t; i < FCHUNK; i += 256)
            atomicAdd(&h[esrc[base + i] >> 7], 1);
        __syncthreads();
        for (int i = t; i < NBUK; i += 256) hist[hb * NBUK + i] = h[i];
    }
}

// --- K2: per bucket, exclusive-scan the FBLK chunk counts (bucket-relative) + total ---
__global__ __launch_bounds__(FBLK) void fillscan_kernel(const int* __restrict__ hist,
                                                        int* __restrict__ blockbase,
                                                        int* __restrict__ total) {
    __shared__ int sc[FBLK];
    int b = blockIdx.x, t = threadIdx.x;
    int own = hist[t * NBUK + b];
    sc[t] = own;
    __syncthreads();
    for (int off = 1; off < FBLK; off <<= 1) {
        int v = (t >= off) ? sc[t - off] : 0;
        __syncthreads();
        sc[t] += v;
        __syncthreads();
    }
    blockbase[b * FBLK + t] = sc[t] - own;     // exclusive, bucket-relative
    if (t == FBLK - 1) total[b] = sc[t];
}

// --- K3: scan 313 bucket totals -> bucketbase[0..313] ---
__global__ __launch_bounds__(512) void bucketscan_kernel(const int* __restrict__ total,
                                                         int* __restrict__ bucketbase) {
    __shared__ int sc[512];
    int t = threadIdx.x;
    int v = (t < NBUK) ? total[t] : 0;
    sc[t] = v;
    __syncthreads();
    for (int off = 1; off < 512; off <<= 1) {
        int u = (t >= off) ? sc[t - off] : 0;
        __syncthreads();
        sc[t] += u;
        __syncthreads();
    }
    if (t < NBUK) bucketbase[t] = sc[t] - v;
    if (t == NBUK - 1) bucketbase[NBUK] = sc[t];   // == NE
}

// --- K4: fillB — stage edges bucket-ordered with contiguous per-(chunk,bucket) runs ---
__global__ __launch_bounds__(256) void fillB_kernel(const int* __restrict__ esrc,
                                                    const int* __restrict__ edst,
                                                    const float* __restrict__ eval_,
                                                    const float* __restrict__ alpha,
                                                    const int* __restrict__ blockbase,
                                                    const int* __restrict__ bucketbase,
                                                    uint2* __restrict__ staged) {
    __shared__ int lcnt[NBUK];
    __shared__ int lbase[NBUK];
    int t = threadIdx.x, blk = blockIdx.x;
    for (int i = t; i < NBUK; i += 256) {
        lcnt[i] = 0;
        lbase[i] = bucketbase[i] + blockbase[i * FBLK + blk];
    }
    __syncthreads();
    int base = blk * FCHUNK;
    for (int i = t; i < FCHUNK; i += 256) {
        int e = base + i;
        int s = esrc[e];
        int d = edst[e];
        float w = alpha[e / E_] * eval_[e];
        int bk = s >> 7;
        int rank = atomicAdd(&lcnt[bk], 1);
        staged[lbase[bk] + rank] = make_uint2((uint)d | ((uint)f2bf(w) << 16), (uint)s);
    }
}

// --- K5: fillC — local row counts, rowptr emit, within-bucket sort to CSR position ---
__global__ __launch_bounds__(256) void fillC_kernel(const uint2* __restrict__ staged,
                                                    const int* __restrict__ bucketbase,
                                                    int* __restrict__ rowptr,
                                                    uint* __restrict__ sorted) {
    __shared__ int cnt128[128];
    __shared__ int cur[128];
    int b = blockIdx.x, t = threadIdx.x;
    if (t < 128) cnt128[t] = 0;
    __syncthreads();
    int beg = bucketbase[b], end = bucketbase[b + 1];
    for (int k = beg + t; k < end; k += 256)
        atomicAdd(&cnt128[staged[k].y & 127], 1);
    __syncthreads();
    if (t < 128) cur[t] = cnt128[t];
    __syncthreads();
    for (int off = 1; off < 128; off <<= 1) {
        int v = 0;
        if (t < 128 && t >= off) v = cur[t - off];
        __syncthreads();
        if (t < 128) cur[t] += v;
        __syncthreads();
    }
    int excl = 0;
    if (t < 128) {
        excl = beg + cur[t] - cnt128[t];       // exclusive row start
        rowptr[(b << 7) + t] = excl;           // coalesced; bucket 312 covers 40000..40063 pad
    }
    __syncthreads();
    if (t < 128) cur[t] = excl;
    __syncthreads();
    for (int k = beg + t; k < end; k += 256) {
        uint2 ed = staged[k];
        int pos = atomicAdd(&cur[ed.y & 127], 1);
        sorted[pos] = ed.x;     // confined to this bucket's ~16KB window
    }
}

// --- K6: CSR SpMM, wave/row, unroll-4 gathers, bf16 proj, fp32 accum ---
__global__ __launch_bounds__(256) void spmm_kernel(const int* __restrict__ rowptr,
                                                   const uint* __restrict__ sorted,
                                                   const ushort* __restrict__ proj,
                                                   float* __restrict__ out) {
    int wave = (blockIdx.x * 256 + threadIdx.x) >> 6;
    int lane = threadIdx.x & 63;
    int beg = __builtin_amdgcn_readfirstlane(rowptr[wave]);
    int end = __builtin_amdgcn_readfirstlane(rowptr[wave + 1]);
    float accx = 0.f, accy = 0.f;
    int j = beg;
    for (; j + 4 <= end; j += 4) {
        uint e0 = sorted[j], e1 = sorted[j + 1], e2 = sorted[j + 2], e3 = sorted[j + 3];
        uint u0 = *(const uint*)&proj[((e0 & 0xffffu) << 7) + 2 * lane];
        uint u1 = *(const uint*)&proj[((e1 & 0xffffu) << 7) + 2 * lane];
        uint u2 = *(const uint*)&proj[((e2 & 0xffffu) << 7) + 2 * lane];
        uint u3 = *(const uint*)&proj[((e3 & 0xffffu) << 7) + 2 * lane];
        float w0 = __uint_as_float(e0 & 0xffff0000u);
        float w1 = __uint_as_float(e1 & 0xffff0000u);
        float w2 = __uint_as_float(e2 & 0xffff0000u);
        float w3 = __uint_as_float(e3 & 0xffff0000u);
        accx += w0 * __uint_as_float(u0 << 16);
        accy += w0 * __uint_as_float(u0 & 0xffff0000u);
        accx += w1 * __uint_as_float(u1 << 16);
        accy += w1 * __uint_as_float(u1 & 0xffff0000u);
        accx += w2 * __uint_as_float(u2 << 16);
        accy += w2 * __uint_as_float(u2 & 0xffff0000u);
        accx += w3 * __uint_as_float(u3 << 16);
        accy += w3 * __uint_as_float(u3 & 0xffff0000u);
    }
    for (; j < end; ++j) {
        uint e = sorted[j];
        uint u = *(const uint*)&proj[((e & 0xffffu) << 7) + 2 * lane];
        float w = __uint_as_float(e & 0xffff0000u);
        accx += w * __uint_as_float(u << 16);
        accy += w * __uint_as_float(u & 0xffff0000u);
    }
    *(float2*)&out[((size_t)wave << 7) + 2 * lane] = make_float2(accx, accy);
}

extern "C" void kernel_launch(void* const* d_in, const int* in_sizes, int n_in,
                              void* d_out, int out_size, void* d_ws, size_t ws_size,
                              hipStream_t stream) {
    const float* ent   = (const float*)d_in[0];
    const float* rel   = (const float*)d_in[1];
    const int*   esrc  = (const int*)d_in[2];
    const int*   edst  = (const int*)d_in[3];
    const float* eval_ = (const float*)d_in[4];
    const float* went  = (const float*)d_in[5];
    const float* w1    = (const float*)d_in[6];
    const float* b1    = (const float*)d_in[7];
    const float* w2    = (const float*)d_in[8];

    float* out      = (float*)d_out;
    float* out_tail = out + (size_t)N_ * F_;

    char* ws = (char*)d_ws;
    size_t off = 0;
    ushort* proj      = (ushort*)(ws + off); off += (size_t)N_ * F_ * 2;     // 10.24 MB
    float* alpha      = (float*)(ws + off);  off += 256;
    int*   rowptr     = (int*)(ws + off);    off += (size_t)(N_ + 64) * 4;   // 160 KB
    uint*  sorted     = (uint*)(ws + off);   off += (size_t)NE * 4;          // 5.12 MB
    uint2* staged     = (uint2*)(ws + off);  off += (size_t)NE * 8;          // 10.24 MB
    int*   hist       = (int*)(ws + off);    off += (size_t)FBLK * NBUK * 4; // 400 KB
    int*   blockbase  = (int*)(ws + off);    off += (size_t)NBUK * FBLK * 4; // 400 KB
    int*   total      = (int*)(ws + off);    off += (size_t)(NBUK + 7) * 4;
    int*   bucketbase = (int*)(ws + off);    off += (size_t)(NBUK + 7) * 4;

    fused_prep<<<950, 256, 0, stream>>>(ent, went, proj, esrc,
                                        rel, out_tail, w1, b1, w2, alpha, hist);
    fillscan_kernel<<<NBUK, FBLK, 0, stream>>>(hist, blockbase, total);
    bucketscan_kernel<<<1, 512, 0, stream>>>(total, bucketbase);
    fillB_kernel<<<FBLK, 256, 0, stream>>>(esrc, edst, eval_, alpha,
                                           blockbase, bucketbase, staged);
    fillC_kernel<<<NBUK, 256, 0, stream>>>(staged, bucketbase, rowptr, sorted);
    spmm_kernel<<<(N_ * 64) / 256, 256, 0, stream>>>(rowptr, sorted, proj, out);
}

// Round 8
// 176.487 us; speedup vs baseline: 3.9266x; 1.1149x over previous
//
#include <hip/hip_runtime.h>

#define R_ 8
#define N_ 40000
#define F_ 128
#define E_ 160000
#define NE (R_ * E_)   // 1,280,000 edges
#define NBUK 313       // src>>7 buckets (128 rows each), 313*128 = 40064 >= N_
#define FBLK 320       // edge chunks
#define FCHUNK 4000    // FBLK * FCHUNK == NE exactly

typedef unsigned short ushort;
typedef unsigned int uint;
typedef __attribute__((ext_vector_type(8))) short bf16x8;
typedef __attribute__((ext_vector_type(4))) float f32x4;

// fp32 -> bf16 round-to-nearest-even (returns bit pattern)
__device__ __forceinline__ ushort f2bf(float x) {
    uint u = __float_as_uint(x);
    return (ushort)((u + 0x7fffu + ((u >> 16) & 1u)) >> 16);
}

// --- K1: fused independent prep ---
// blocks [0,625):    proj = ent @ W  via bf16 MFMA (64 rows/block)
// block  625:        rel_mat passthrough to out tail
// blocks [626,630):  alpha MLP (2 relations/block)
// blocks [630,950):  fillA — per-chunk bucket histogram (313 buckets)
__global__ __launch_bounds__(256) void fused_prep(
        const float* __restrict__ ent, const float* __restrict__ W,
        ushort* __restrict__ proj,
        const int* __restrict__ esrc,
        const float* __restrict__ rel, float* __restrict__ out_tail,
        const float* __restrict__ w1, const float* __restrict__ b1,
        const float* __restrict__ w2, float* __restrict__ alpha,
        int* __restrict__ hist) {
    __shared__ float smem[64 * F_];          // 32 KB; proj aliases as ushort Wt[128][128]
    const int t = threadIdx.x;
    const int b = blockIdx.x;
    if (b < 625) {
        ushort* Wt = (ushort*)smem;          // W^T bf16, row n (col of W), chunk-XOR swizzle
        // transpose-convert W (128x128 fp32) -> Wt. 16 passes of 8 k-rows.
#pragma unroll
        for (int p = 0; p < 16; ++p) {
            int k = p * 8 + (t >> 5);
            int c4 = (t & 31) * 4;
            float4 wv = *(const float4*)&W[k * F_ + c4];
#pragma unroll
            for (int i = 0; i < 4; ++i) {
                int col = c4 + i;
                float v = (i == 0) ? wv.x : (i == 1) ? wv.y : (i == 2) ? wv.z : wv.w;
                // element k of row col; chunk = k>>3 xor (col&7), offset k&7
                Wt[col * F_ + ((((k >> 3) ^ (col & 7)) << 3) | (k & 7))] = f2bf(v);
            }
        }
        __syncthreads();
        const int wv_ = t >> 6;              // wave 0..3
        const int lane = t & 63;
        const int m = lane & 15;             // A row within 16-tile
        const int q = (lane >> 4) & 3;       // quad
        const int row0 = b * 64 + wv_ * 16;
        // A fragments: 4 K-chunks of 32, lane reads ent[row0+m][kc*32+q*8 .. +8) fp32
        bf16x8 afrag[4];
        const float* arow = ent + (size_t)(row0 + m) * F_;
#pragma unroll
        for (int kc = 0; kc < 4; ++kc) {
            float4 a0 = *(const float4*)&arow[kc * 32 + q * 8];
            float4 a1 = *(const float4*)&arow[kc * 32 + q * 8 + 4];
            bf16x8 a;
            a[0] = (short)f2bf(a0.x); a[1] = (short)f2bf(a0.y);
            a[2] = (short)f2bf(a0.z); a[3] = (short)f2bf(a0.w);
            a[4] = (short)f2bf(a1.x); a[5] = (short)f2bf(a1.y);
            a[6] = (short)f2bf(a1.z); a[7] = (short)f2bf(a1.w);
            afrag[kc] = a;
        }
        // 8 col-tiles x 4 K-chunks of MFMA
        f32x4 acc[8];
#pragma unroll
        for (int ct = 0; ct < 8; ++ct) acc[ct] = (f32x4){0.f, 0.f, 0.f, 0.f};
#pragma unroll
        for (int ct = 0; ct < 8; ++ct) {
            int n = ct * 16 + m;             // Wt row = W column
#pragma unroll
            for (int kc = 0; kc < 4; ++kc) {
                int chunk = kc * 4 + q;
                bf16x8 bfrag = *(const bf16x8*)&Wt[n * F_ + ((chunk ^ (n & 7)) << 3)];
                acc[ct] = __builtin_amdgcn_mfma_f32_16x16x32_bf16(afrag[kc], bfrag, acc[ct], 0, 0, 0);
            }
        }
        // epilogue: D col = ct*16 + (lane&15), row = q*4 + reg
#pragma unroll
        for (int ct = 0; ct < 8; ++ct) {
#pragma unroll
            for (int reg = 0; reg < 4; ++reg) {
                int row = row0 + q * 4 + reg;
                proj[(size_t)row * F_ + ct * 16 + m] = f2bf(acc[ct][reg]);
            }
        }
    } else if (b == 625) {
        ((float4*)out_tail)[t] = ((const float4*)rel)[t];   // 1024 floats
    } else if (b < 630) {
        int r = (b - 626) * 2 + (t >> 7);
        int o = t & 127;
        float s = 0.f;
#pragma unroll 8
        for (int f = 0; f < F_; ++f) s += rel[r * F_ + f] * w1[f * F_ + o];
        float h = tanhf(s + b1[o]);
        smem[t] = h * w2[o];
        __syncthreads();
        for (int off = 64; off > 0; off >>= 1) {
            if ((t & 127) < off) smem[t] += smem[t + off];
            __syncthreads();
        }
        if ((t & 127) == 0) alpha[r] = 1.f / (1.f + expf(-smem[t]));
    } else {
        // fillA: bucket histogram for chunk hb
        int hb = b - 630;
        int* h = (int*)smem;
        for (int i = t; i < NBUK; i += 256) h[i] = 0;
        __syncthreads();
        int base = hb * FCHUNK;
        for (int i = t; i < FCHUNK; i += 256)
            atomicAdd(&h[esrc[base + i] >> 7], 1);
        __syncthreads();
        for (int i = t; i < NBUK; i += 256) hist[hb * NBUK + i] = h[i];
    }
}

// --- K2: per bucket, exclusive-scan the FBLK chunk counts (bucket-relative) + total ---
__global__ __launch_bounds__(FBLK) void fillscan_kernel(const int* __restrict__ hist,
                                                        int* __restrict__ blockbase,
                                                        int* __restrict__ total) {
    __shared__ int sc[FBLK];
    int b = blockIdx.x, t = threadIdx.x;
    int own = hist[t * NBUK + b];
    sc[t] = own;
    __syncthreads();
    for (int off = 1; off < FBLK; off <<= 1) {
        int v = (t >= off) ? sc[t - off] : 0;
        __syncthreads();
        sc[t] += v;
        __syncthreads();
    }
    blockbase[b * FBLK + t] = sc[t] - own;     // exclusive, bucket-relative
    if (t == FBLK - 1) total[b] = sc[t];
}

// --- K3: scan 313 bucket totals -> bucketbase[0..313] ---
__global__ __launch_bounds__(512) void bucketscan_kernel(const int* __restrict__ total,
                                                         int* __restrict__ bucketbase) {
    __shared__ int sc[512];
    int t = threadIdx.x;
    int v = (t < NBUK) ? total[t] : 0;
    sc[t] = v;
    __syncthreads();
    for (int off = 1; off < 512; off <<= 1) {
        int u = (t >= off) ? sc[t - off] : 0;
        __syncthreads();
        sc[t] += u;
        __syncthreads();
    }
    if (t < NBUK) bucketbase[t] = sc[t] - v;
    if (t == NBUK - 1) bucketbase[NBUK] = sc[t];   // == NE
}

// --- K4: fillB — stage edges bucket-ordered with contiguous per-(chunk,bucket) runs ---
__global__ __launch_bounds__(256) void fillB_kernel(const int* __restrict__ esrc,
                                                    const int* __restrict__ edst,
                                                    const float* __restrict__ eval_,
                                                    const float* __restrict__ alpha,
                                                    const int* __restrict__ blockbase,
                                                    const int* __restrict__ bucketbase,
                                                    uint2* __restrict__ staged) {
    __shared__ int lcnt[NBUK];
    __shared__ int lbase[NBUK];
    int t = threadIdx.x, blk = blockIdx.x;
    for (int i = t; i < NBUK; i += 256) {
        lcnt[i] = 0;
        lbase[i] = bucketbase[i] + blockbase[i * FBLK + blk];
    }
    __syncthreads();
    int base = blk * FCHUNK;
    for (int i = t; i < FCHUNK; i += 256) {
        int e = base + i;
        int s = esrc[e];
        int d = edst[e];
        float w = alpha[e / E_] * eval_[e];
        int bk = s >> 7;
        int rank = atomicAdd(&lcnt[bk], 1);
        staged[lbase[bk] + rank] = make_uint2((uint)d | ((uint)f2bf(w) << 16), (uint)s);
    }
}

// --- K5: fillC — local row counts, rowptr emit, within-bucket sort to CSR position ---
__global__ __launch_bounds__(256) void fillC_kernel(const uint2* __restrict__ staged,
                                                    const int* __restrict__ bucketbase,
                                                    int* __restrict__ rowptr,
                                                    uint* __restrict__ sorted) {
    __shared__ int cnt128[128];
    __shared__ int cur[128];
    int b = blockIdx.x, t = threadIdx.x;
    if (t < 128) cnt128[t] = 0;
    __syncthreads();
    int beg = bucketbase[b], end = bucketbase[b + 1];
    for (int k = beg + t; k < end; k += 256)
        atomicAdd(&cnt128[staged[k].y & 127], 1);
    __syncthreads();
    if (t < 128) cur[t] = cnt128[t];
    __syncthreads();
    for (int off = 1; off < 128; off <<= 1) {
        int v = 0;
        if (t < 128 && t >= off) v = cur[t - off];
        __syncthreads();
        if (t < 128) cur[t] += v;
        __syncthreads();
    }
    int excl = 0;
    if (t < 128) {
        excl = beg + cur[t] - cnt128[t];       // exclusive row start
        rowptr[(b << 7) + t] = excl;           // coalesced
    }
    __syncthreads();
    if (t < 128) cur[t] = excl;
    __syncthreads();
    for (int k = beg + t; k < end; k += 256) {
        uint2 ed = staged[k];
        int pos = atomicAdd(&cur[ed.y & 127], 1);
        sorted[pos] = ed.x;     // confined to this bucket's ~16KB window
    }
}

// --- K6: CSR SpMM, wave/row, unroll-4 gathers, bf16 proj, fp32 accum ---
__global__ __launch_bounds__(256) void spmm_kernel(const int* __restrict__ rowptr,
                                                   const uint* __restrict__ sorted,
                                                   const ushort* __restrict__ proj,
                                                   float* __restrict__ out) {
    int wave = (blockIdx.x * 256 + threadIdx.x) >> 6;
    int lane = threadIdx.x & 63;
    int beg = __builtin_amdgcn_readfirstlane(rowptr[wave]);
    int end = __builtin_amdgcn_readfirstlane(rowptr[wave + 1]);
    float accx = 0.f, accy = 0.f;
    int j = beg;
    for (; j + 4 <= end; j += 4) {
        uint e0 = sorted[j], e1 = sorted[j + 1], e2 = sorted[j + 2], e3 = sorted[j + 3];
        uint u0 = *(const uint*)&proj[((e0 & 0xffffu) << 7) + 2 * lane];
        uint u1 = *(const uint*)&proj[((e1 & 0xffffu) << 7) + 2 * lane];
        uint u2 = *(const uint*)&proj[((e2 & 0xffffu) << 7) + 2 * lane];
        uint u3 = *(const uint*)&proj[((e3 & 0xffffu) << 7) + 2 * lane];
        float w0 = __uint_as_float(e0 & 0xffff0000u);
        float w1 = __uint_as_float(e1 & 0xffff0000u);
        float w2 = __uint_as_float(e2 & 0xffff0000u);
        float w3 = __uint_as_float(e3 & 0xffff0000u);
        accx += w0 * __uint_as_float(u0 << 16);
        accy += w0 * __uint_as_float(u0 & 0xffff0000u);
        accx += w1 * __uint_as_float(u1 << 16);
        accy += w1 * __uint_as_float(u1 & 0xffff0000u);
        accx += w2 * __uint_as_float(u2 << 16);
        accy += w2 * __uint_as_float(u2 & 0xffff0000u);
        accx += w3 * __uint_as_float(u3 << 16);
        accy += w3 * __uint_as_float(u3 & 0xffff0000u);
    }
    for (; j < end; ++j) {
        uint e = sorted[j];
        uint u = *(const uint*)&proj[((e & 0xffffu) << 7) + 2 * lane];
        float w = __uint_as_float(e & 0xffff0000u);
        accx += w * __uint_as_float(u << 16);
        accy += w * __uint_as_float(u & 0xffff0000u);
    }
    *(float2*)&out[((size_t)wave << 7) + 2 * lane] = make_float2(accx, accy);
}

extern "C" void kernel_launch(void* const* d_in, const int* in_sizes, int n_in,
                              void* d_out, int out_size, void* d_ws, size_t ws_size,
                              hipStream_t stream) {
    const float* ent   = (const float*)d_in[0];
    const float* rel   = (const float*)d_in[1];
    const int*   esrc  = (const int*)d_in[2];
    const int*   edst  = (const int*)d_in[3];
    const float* eval_ = (const float*)d_in[4];
    const float* went  = (const float*)d_in[5];
    const float* w1    = (const float*)d_in[6];
    const float* b1    = (const float*)d_in[7];
    const float* w2    = (const float*)d_in[8];

    float* out      = (float*)d_out;
    float* out_tail = out + (size_t)N_ * F_;

    char* ws = (char*)d_ws;
    size_t off = 0;
    ushort* proj      = (ushort*)(ws + off); off += (size_t)N_ * F_ * 2;     // 10.24 MB
    float* alpha      = (float*)(ws + off);  off += 256;
    int*   rowptr     = (int*)(ws + off);    off += (size_t)(N_ + 64) * 4;   // 160 KB
    uint*  sorted     = (uint*)(ws + off);   off += (size_t)NE * 4;          // 5.12 MB
    uint2* staged     = (uint2*)(ws + off);  off += (size_t)NE * 8;          // 10.24 MB
    int*   hist       = (int*)(ws + off);    off += (size_t)FBLK * NBUK * 4; // 400 KB
    int*   blockbase  = (int*)(ws + off);    off += (size_t)NBUK * FBLK * 4; // 400 KB
    int*   total      = (int*)(ws + off);    off += (size_t)(NBUK + 7) * 4;
    int*   bucketbase = (int*)(ws + off);    off += (size_t)(NBUK + 7) * 4;

    fused_prep<<<950, 256, 0, stream>>>(ent, went, proj, esrc,
                                        rel, out_tail, w1, b1, w2, alpha, hist);
    fillscan_kernel<<<NBUK, FBLK, 0, stream>>>(hist, blockbase, total);
    bucketscan_kernel<<<1, 512, 0, stream>>>(total, bucketbase);
    fillB_kernel<<<FBLK, 256, 0, stream>>>(esrc, edst, eval_, alpha,
                                           blockbase, bucketbase, staged);
    fillC_kernel<<<NBUK, 256, 0, stream>>>(staged, bucketbase, rowptr, sorted);
    spmm_kernel<<<(N_ * 64) / 256, 256, 0, stream>>>(rowptr, sorted, proj, out);
}